// Round 19
// baseline (104.209 us; speedup 1.0000x reference)
//
#include <hip/hip_runtime.h>
#include <hip/hip_bf16.h>

#define N_TOK 8192
#define D_IN  1024
#define DK    128
#define NT    256   // number of 32-row q tiles (== number of 32-row kv tiles)

typedef __attribute__((ext_vector_type(8))) short short8;
typedef __attribute__((ext_vector_type(4))) float f32x4;

static __device__ __forceinline__ unsigned short f2bf(float f) {
    __hip_bfloat16 h = __float2bfloat16(f);
    return __builtin_bit_cast(unsigned short, h);
}

static __device__ __forceinline__ void gl_lds16(const void* g, void* l) {
    __builtin_amdgcn_global_load_lds(
        (const __attribute__((address_space(1))) void*)g,
        (__attribute__((address_space(3))) void*)l, 16, 0, 0);
}

// ---------------- one-time W transpose: W[k][n] f32 -> Wt[n][k] bf16 ----------------
__global__ __launch_bounds__(256) void wtrans_kernel(
    const float* __restrict__ Wq, const float* __restrict__ Wk,
    const float* __restrict__ Wv, unsigned short* __restrict__ Wt)
{
    __shared__ unsigned short T[64][72];
    const int proj = blockIdx.y;
    const float* W = (proj == 0) ? Wq : (proj == 1) ? Wk : Wv;
    unsigned short* out = Wt + (size_t)proj * DK * D_IN;
    const int k0 = (blockIdx.x & 15) * 64, n0 = (blockIdx.x >> 4) * 64;
    const int tid = threadIdx.x;
    #pragma unroll
    for (int i = 0; i < 4; i++) {
        int e = tid + i * 256;
        int r = e >> 4, c4 = e & 15;
        float4 v = *reinterpret_cast<const float4*>(&W[(size_t)(k0 + r) * DK + n0 + c4 * 4]);
        T[c4 * 4 + 0][r] = f2bf(v.x);
        T[c4 * 4 + 1][r] = f2bf(v.y);
        T[c4 * 4 + 2][r] = f2bf(v.z);
        T[c4 * 4 + 3][r] = f2bf(v.w);
    }
    __syncthreads();
    #pragma unroll
    for (int i = 0; i < 4; i++) {
        int e = tid + i * 256;
        int r = e >> 4, c4 = e & 15;
        *reinterpret_cast<ushort4*>(&out[(size_t)(n0 + r) * D_IN + k0 + c4 * 4]) =
            *reinterpret_cast<const ushort4*>(&T[r][c4 * 4]);
    }
}

// ---------------- fused QKV projection: W stationary, X f32 direct, BK=128 ------
// grid = 1536 = 256 row-blocks(32 rows) x 6 col-groups(64 cols), XCD-clustered
// (the 6 cg blocks of one rb share an XCD -> X slice L2-resident). 8 k-steps
// of 128. X staged f32->bf16 via regs + swizzled ds_write (blk^(row&7)).
// Q plain row-major; K 16B-block-swizzled; V transposed [d][kv] + (d&3) swizzle.
__global__ __launch_bounds__(256, 2) void proj_fused(
    const float* __restrict__ X, const unsigned short* __restrict__ Wt,
    const float* __restrict__ bq, const float* __restrict__ bk,
    const float* __restrict__ bv,
    unsigned short* __restrict__ Qb, unsigned short* __restrict__ Kb,
    unsigned short* __restrict__ Vt)
{
    __shared__ unsigned short Xs[2][32][128];   // 2 x 8 KB bf16

    const int bid = blockIdx.x;
    const int t2 = bid >> 3;
    const int rb = (t2 / 6) * 8 + (bid & 7);   // 0..255
    const int cg = t2 % 6;                     // 0..5

    const int tid = threadIdx.x;
    const int wid = tid >> 6, lane = tid & 63;
    const int g = lane >> 4, r16 = lane & 15;
    const int mb = rb * 32;
    const int colv = cg * 64 + wid * 16 + r16;   // global output col 0..383
    const int pj = colv >> 7;
    const int n  = colv & 127;

    // ---- W -> registers (once): 32 k-frags for this lane's column ----
    short8 wf[32];
    #pragma unroll
    for (int kd = 0; kd < 32; kd++)
        wf[kd] = *reinterpret_cast<const short8*>(
            &Wt[((size_t)pj * DK + n) * D_IN + kd * 32 + g * 8]);

    f32x4 acc[2] = {};   // 32 rows = 2 x 16-row frags, 16 cols

    // reg-staged X: 4 float4 per thread per step (32x128 f32 tile)
    float4 xr[4];
    const int xr_c4 = tid & 31;        // f32 float4-group 0..31
    auto XLOAD = [&](int s) {
        #pragma unroll
        for (int i = 0; i < 4; i++) {
            int r = (tid + i * 256) >> 5;          // 0..31
            xr[i] = *reinterpret_cast<const float4*>(
                &X[(size_t)(mb + r) * D_IN + s * 128 + xr_c4 * 4]);
        }
    };
    auto XWRITE = [&](int buf) {
        #pragma unroll
        for (int i = 0; i < 4; i++) {
            int r = (tid + i * 256) >> 5;
            ushort4 h;
            h.x = f2bf(xr[i].x); h.y = f2bf(xr[i].y);
            h.z = f2bf(xr[i].z); h.w = f2bf(xr[i].w);
            // 16B-bf16 block = c4>>1 (0..15), half = c4&1; swizzle low3 by row&7
            int off = (((xr_c4 >> 1) ^ (r & 7)) << 3) | ((xr_c4 & 1) << 2);
            *reinterpret_cast<ushort4*>(&Xs[buf][r][off]) = h;
        }
    };

    XLOAD(0); XWRITE(0);
    __syncthreads();
    #pragma unroll
    for (int s = 0; s < 8; ++s) {
        const int cur = s & 1;
        if (s + 1 < 8) XLOAD(s + 1);           // global->reg, overlaps compute
        #pragma unroll
        for (int kk = 0; kk < 4; kk++) {
            short8 af[2];
            #pragma unroll
            for (int mi = 0; mi < 2; mi++) {
                int blk = ((kk << 2) | g) ^ (r16 & 7);
                af[mi] = *reinterpret_cast<const short8*>(
                    &Xs[cur][mi * 16 + r16][blk * 8]);
            }
            __builtin_amdgcn_s_setprio(1);
            #pragma unroll
            for (int mi = 0; mi < 2; mi++)
                acc[mi] = __builtin_amdgcn_mfma_f32_16x16x32_bf16(
                    af[mi], wf[4 * s + kk], acc[mi], 0, 0, 0);
            __builtin_amdgcn_s_setprio(0);
        }
        if (s + 1 < 8) XWRITE((s + 1) & 1);    // buf^1: its reads ended last barrier
        __syncthreads();
    }

    const float* bias = (pj == 0) ? bq : (pj == 1) ? bk : bv;
    float b = bias[n];
    #pragma unroll
    for (int mi = 0; mi < 2; mi++) {
        if (pj < 2) {
            unsigned short* out = (pj == 0) ? Qb : Kb;
            #pragma unroll
            for (int e = 0; e < 4; e++) {
                int m = mb + mi * 16 + g * 4 + e;
                float val = acc[mi][e] + b;
                int nc = n;
                if (pj == 1)   // K swizzle: 16B block ^= (kv&7)
                    nc = ((((n >> 3) ^ (m & 7)) << 3) | (n & 7));
                out[(size_t)m * DK + nc] = f2bf(val);
            }
        } else {
            int m0 = mb + mi * 16 + g * 4;
            // V swizzle within 32-kv group: block' = ((m&31)>>3) ^ (d&3)
            int mblk = (((m0 & 31) >> 3) ^ (n & 3));
            int mp = (m0 & ~31) | (mblk << 3) | (m0 & 7);
            ushort4 h;
            h.x = f2bf(acc[mi][0] + b);
            h.y = f2bf(acc[mi][1] + b);
            h.z = f2bf(acc[mi][2] + b);
            h.w = f2bf(acc[mi][3] + b);
            *reinterpret_cast<ushort4*>(&Vt[(size_t)n * N_TOK + mp]) = h;
        }
    }
}

// ---------------- causal flash attention (R6/R13 champion, 56 µs) ----------------
// grid = (64 q-blocks, max_chunks). Block (qb,c): q rows [qb*128,+128), kv tiles
// [c*ct, min((c+1)*ct, 4qb+4)). 4 waves each own 32 q rows, share LDS K/V.
// Double-buffered global_load_lds with counted vmcnt(4); P via wave-private LDS;
// bf16 partials.
__global__ __launch_bounds__(256, 3) void attn_partial(
    const unsigned short* __restrict__ Qb, const unsigned short* __restrict__ Ksw,
    const unsigned short* __restrict__ Vsw,
    unsigned short* __restrict__ OpartH, float* __restrict__ Mpart,
    float* __restrict__ Lpart,
    float* __restrict__ O, int chunk_tiles, int max_chunks, int direct)
{
    __shared__ unsigned short Klds[2][32][128];   // 16 KB
    __shared__ unsigned short Vlds[2][128][32];   // 16 KB
    __shared__ unsigned short Pq[4][32][36];      // 9.2 KB, per-wave P[q][kv]

    const int qb = blockIdx.x, c = blockIdx.y;
    const int j0 = c * chunk_tiles;
    const int jmax = 4 * qb + 4;
    const int jend = min(j0 + chunk_tiles, jmax);
    if (j0 >= jend) return;
    const int nt = jend - j0;

    const int tid = threadIdx.x;
    const int wid = tid >> 6, lane = tid & 63;
    const int g = lane >> 4, r16 = lane & 15;
    const int t = qb * 4 + wid;     // this wave's 32-row q tile index
    const int qw = t * 32;          // global q base of this wave
    const float scale2 = 0.08838834764831845f * 1.4426950408889634f; // /sqrt(dk)*log2e

    auto STAGE = [&](int buf, int kvb) {   // exactly 4 gl_lds per thread
        #pragma unroll
        for (int s = 0; s < 2; s++) {                  // K: 8KB linear copy
            int ob = ((wid * 2 + s) << 10);
            gl_lds16((const char*)Ksw + ((size_t)kvb << 8) + ob + (lane << 4),
                     (char*)&Klds[buf][0][0] + ob);
        }
        #pragma unroll
        for (int s = 0; s < 2; s++) {                  // V: 128 rows x 64B
            int ob = ((wid * 2 + s) << 10);
            int o = ob + (lane << 4);
            int d = o >> 6, cb = o & 63;
            gl_lds16((const char*)Vsw + (((size_t)d * N_TOK + kvb) << 1) + cb,
                     (char*)&Vlds[buf][0][0] + ob);
        }
    };

    // Q fragments (B-operand): col=q=mi*16+r16, k=d
    short8 qf[2][4];
    #pragma unroll
    for (int mi = 0; mi < 2; mi++)
        #pragma unroll
        for (int kd = 0; kd < 4; kd++)
            qf[mi][kd] = *reinterpret_cast<const short8*>(
                &Qb[(size_t)(qw + mi * 16 + r16) * DK + kd * 32 + g * 8]);

    f32x4 o_acc[2][8] = {};                  // O^T: [q-frag mi][d-frag df]
    float m_run[2] = {-1e30f, -1e30f}, l_run[2] = {0.f, 0.f};

    STAGE(0, j0 * 32);

    int cur = 0;
    for (int it = 0; it < nt; ++it) {
        const int kvb = (j0 + it) * 32;
        if (it + 1 < nt) {
            STAGE(cur ^ 1, kvb + 32);
            asm volatile("s_waitcnt vmcnt(4)" ::: "memory");   // tile it landed
        } else {
            asm volatile("s_waitcnt vmcnt(0)" ::: "memory");
        }
        __builtin_amdgcn_sched_barrier(0);
        __builtin_amdgcn_s_barrier();
        __builtin_amdgcn_sched_barrier(0);

        const unsigned short* Kl = &Klds[cur][0][0];
        const unsigned short* Vl = &Vlds[cur][0][0];

        // ---- S^T = K Q^T from LDS (swizzled reads) ----
        f32x4 st[2][2] = {};                 // [ni=kv frag][mi=q frag]
        #pragma unroll
        for (int kd = 0; kd < 4; kd++) {
            int swb = ((((kd << 2) | g) ^ (r16 & 7)) << 3);
            short8 kf0 = *reinterpret_cast<const short8*>(Kl + r16 * 128 + swb);
            short8 kf1 = *reinterpret_cast<const short8*>(Kl + (16 + r16) * 128 + swb);
            __builtin_amdgcn_s_setprio(1);
            st[0][0] = __builtin_amdgcn_mfma_f32_16x16x32_bf16(kf0, qf[0][kd], st[0][0], 0, 0, 0);
            st[0][1] = __builtin_amdgcn_mfma_f32_16x16x32_bf16(kf0, qf[1][kd], st[0][1], 0, 0, 0);
            st[1][0] = __builtin_amdgcn_mfma_f32_16x16x32_bf16(kf1, qf[0][kd], st[1][0], 0, 0, 0);
            st[1][1] = __builtin_amdgcn_mfma_f32_16x16x32_bf16(kf1, qf[1][kd], st[1][1], 0, 0, 0);
            __builtin_amdgcn_s_setprio(0);
        }

        // ---- online softmax (exp2 domain), per q-column (mi,r16) ----
        const bool anymask = (kvb + 31 > qw);
        float alpha[2];
        #pragma unroll
        for (int mi = 0; mi < 2; mi++) {
            const int qrow = qw + mi * 16 + r16;
            float s[2][4];
            #pragma unroll
            for (int ni = 0; ni < 2; ni++)
                #pragma unroll
                for (int e = 0; e < 4; e++) {
                    float v = st[ni][mi][e] * scale2;
                    if (anymask && (kvb + ni * 16 + g * 4 + e > qrow)) v = -1e30f;
                    s[ni][e] = v;
                }
            float lm = fmaxf(fmaxf(fmaxf(s[0][0], s[0][1]), fmaxf(s[0][2], s[0][3])),
                             fmaxf(fmaxf(s[1][0], s[1][1]), fmaxf(s[1][2], s[1][3])));
            lm = fmaxf(lm, __shfl_xor(lm, 16));
            lm = fmaxf(lm, __shfl_xor(lm, 32));
            float mnew = fmaxf(m_run[mi], lm);
            alpha[mi] = exp2f(m_run[mi] - mnew);
            float ps[2][4];
            #pragma unroll
            for (int ni = 0; ni < 2; ni++)
                #pragma unroll
                for (int e = 0; e < 4; e++)
                    ps[ni][e] = exp2f(s[ni][e] - mnew);
            float ls = ((ps[0][0] + ps[0][1]) + (ps[0][2] + ps[0][3]))
                     + ((ps[1][0] + ps[1][1]) + (ps[1][2] + ps[1][3]));
            ls += __shfl_xor(ls, 16);
            ls += __shfl_xor(ls, 32);
            l_run[mi] = l_run[mi] * alpha[mi] + ls;
            m_run[mi] = mnew;
            #pragma unroll
            for (int ni = 0; ni < 2; ni++) {
                ushort4 pk;
                pk.x = f2bf(ps[ni][0]); pk.y = f2bf(ps[ni][1]);
                pk.z = f2bf(ps[ni][2]); pk.w = f2bf(ps[ni][3]);
                *reinterpret_cast<ushort4*>(&Pq[wid][mi * 16 + r16][ni * 16 + g * 4]) = pk;
            }
        }
        if (__any(alpha[0] < 1.f) || __any(alpha[1] < 1.f)) {
            #pragma unroll
            for (int mi = 0; mi < 2; mi++)
                #pragma unroll
                for (int df = 0; df < 8; df++)
                    #pragma unroll
                    for (int e = 0; e < 4; e++)
                        o_acc[mi][df][e] *= alpha[mi];
        }
        // P^T B-fragments: col=q=r16, k=kv=g*8+idx (wave-private Pq: no barrier)
        short8 pb0 = *reinterpret_cast<const short8*>(&Pq[wid][r16][g * 8]);
        short8 pb1 = *reinterpret_cast<const short8*>(&Pq[wid][16 + r16][g * 8]);
        // ---- O^T += V^T P^T, V from LDS (swizzled reads) ----
        const int swv = ((g ^ (r16 & 3)) << 3);
        #pragma unroll
        for (int df = 0; df < 8; df++) {
            short8 vf = *reinterpret_cast<const short8*>(Vl + (df * 16 + r16) * 32 + swv);
            __builtin_amdgcn_s_setprio(1);
            o_acc[0][df] = __builtin_amdgcn_mfma_f32_16x16x32_bf16(vf, pb0, o_acc[0][df], 0, 0, 0);
            o_acc[1][df] = __builtin_amdgcn_mfma_f32_16x16x32_bf16(vf, pb1, o_acc[1][df], 0, 0, 0);
            __builtin_amdgcn_s_setprio(0);
        }

        __builtin_amdgcn_sched_barrier(0);
        __builtin_amdgcn_s_barrier();      // all waves done reading buf[cur]
        __builtin_amdgcn_sched_barrier(0);
        cur ^= 1;
    }

    // ---- epilogue: direct f32 out, else bf16 partials ----
    if (direct) {
        #pragma unroll
        for (int mi = 0; mi < 2; mi++) {
            float inv = 1.0f / l_run[mi];
            #pragma unroll
            for (int df = 0; df < 8; df++) {
                f32x4 r = o_acc[mi][df];
                r[0] *= inv; r[1] *= inv; r[2] *= inv; r[3] *= inv;
                *reinterpret_cast<f32x4*>(
                    &O[(size_t)(qw + mi * 16 + r16) * DK + df * 16 + g * 4]) = r;
            }
        }
    } else {
        size_t pb0i = ((size_t)t * max_chunks + c) * 32;
        #pragma unroll
        for (int mi = 0; mi < 2; mi++) {
            int q = mi * 16 + r16;
            #pragma unroll
            for (int df = 0; df < 8; df++) {
                ushort4 h;
                h.x = f2bf(o_acc[mi][df][0]); h.y = f2bf(o_acc[mi][df][1]);
                h.z = f2bf(o_acc[mi][df][2]); h.w = f2bf(o_acc[mi][df][3]);
                *reinterpret_cast<ushort4*>(
                    &OpartH[(pb0i + q) * 128 + df * 16 + g * 4]) = h;
            }
            if (g == 0) { Mpart[pb0i + q] = m_run[mi]; Lpart[pb0i + q] = l_run[mi]; }
        }
    }
}

// ---------------- merge bf16 partials across chunks (exp2, d-split 2x) ----------
// grid = (NT, 2): block (t, half) merges rows of q-tile t for cols half*64..+64.
__global__ __launch_bounds__(256) void attn_merge(
    const unsigned short* __restrict__ OpartH, const float* __restrict__ Mpart,
    const float* __restrict__ Lpart, float* __restrict__ O,
    int chunk_tiles, int max_chunks)
{
    __shared__ float Ms[32], Ls[32], Fs[16][32];
    const int t = blockIdx.x;
    const int half = blockIdx.y;
    const int nc = t / chunk_tiles + 1;
    const int tid = threadIdx.x;

    if (tid < 32) {
        float M = -1e30f;
        for (int c = 0; c < nc; c++)
            M = fmaxf(M, Mpart[((size_t)t * max_chunks + c) * 32 + tid]);
        float L = 0.f;
        for (int c = 0; c < nc; c++) {
            size_t pb = ((size_t)t * max_chunks + c) * 32 + tid;
            L += exp2f(Mpart[pb] - M) * Lpart[pb];
        }
        Ms[tid] = M; Ls[tid] = L;
    }
    __syncthreads();
    for (int cc = tid >> 5; cc < nc; cc += 8) {
        int row = tid & 31;
        Fs[cc][row] = exp2f(Mpart[((size_t)t * max_chunks + cc) * 32 + row] - Ms[row]);
    }
    __syncthreads();
    {
        int row = tid >> 3;                       // 32 rows x 8 col-groups of 8
        int c8 = (tid & 7) + half * 8;            // this block's 64-col half
        float accv[8] = {};
        for (int c = 0; c < nc; c++) {
            short8 u = *reinterpret_cast<const short8*>(
                &OpartH[(((size_t)t * max_chunks + c) * 32 + row) * 128 + c8 * 8]);
            float f = Fs[c][row];
            #pragma unroll
            for (int k = 0; k < 8; k++) {
                unsigned uv = ((unsigned)(unsigned short)u[k]) << 16;
                accv[k] += f * __builtin_bit_cast(float, uv);
            }
        }
        float inv = 1.0f / Ls[row];
        float* dst = &O[((size_t)t * 32 + row) * DK + c8 * 8];
        float4 r0 = {accv[0] * inv, accv[1] * inv, accv[2] * inv, accv[3] * inv};
        float4 r1 = {accv[4] * inv, accv[5] * inv, accv[6] * inv, accv[7] * inv};
        *reinterpret_cast<float4*>(dst) = r0;
        *reinterpret_cast<float4*>(dst + 4) = r1;
    }
}

extern "C" void kernel_launch(void* const* d_in, const int* in_sizes, int n_in,
                              void* d_out, int out_size, void* d_ws, size_t ws_size,
                              hipStream_t stream) {
    const float* X  = (const float*)d_in[0];
    const float* Wq = (const float*)d_in[1];
    const float* bq = (const float*)d_in[2];
    const float* Wk = (const float*)d_in[3];
    const float* bk = (const float*)d_in[4];
    const float* Wv = (const float*)d_in[5];
    const float* bv = (const float*)d_in[6];
    float* O = (float*)d_out;

    unsigned short* Qb = (unsigned short*)d_ws;
    unsigned short* Kb = Qb + (size_t)N_TOK * DK;
    unsigned short* Vt = Kb + (size_t)N_TOK * DK;
    unsigned short* Wt = Vt + (size_t)N_TOK * DK;
    float* Mbase = (float*)(Wt + (size_t)3 * DK * D_IN);
    size_t base_bytes = (size_t)((char*)Mbase - (char*)d_ws);

    // ladder: pick smallest chunk whose partials fit ws
    int chunk_tiles = 0, max_chunks = 1, direct = 0;
    const int opts[4] = {16, 32, 64, 128};
    for (int i = 0; i < 4; i++) {
        int ct = opts[i], mc = NT / ct;
        size_t need = base_bytes
                    + (size_t)NT * mc * 32 * 2 * sizeof(float)      // M, L
                    + (size_t)NT * mc * 32 * 128 * 2;               // Opart bf16
        if (need <= ws_size) { chunk_tiles = ct; max_chunks = mc; break; }
    }
    if (!chunk_tiles) { chunk_tiles = NT; max_chunks = 1; direct = 1; }
    float* Mpart = Mbase;
    float* Lpart = Mpart + (size_t)NT * max_chunks * 32;
    unsigned short* OpartH = (unsigned short*)(Lpart + (size_t)NT * max_chunks * 32);

    wtrans_kernel<<<dim3(32, 3), 256, 0, stream>>>(Wq, Wk, Wv, Wt);
    proj_fused<<<dim3(1536), 256, 0, stream>>>(X, Wt, bq, bk, bv, Qb, Kb, Vt);
    int grid_c = direct ? 1 : max_chunks;
    attn_partial<<<dim3(64, grid_c), 256, 0, stream>>>(
        Qb, Kb, Vt, OpartH, Mpart, Lpart, O, chunk_tiles, max_chunks, direct);
    if (!direct)
        attn_merge<<<dim3(NT, 2), 256, 0, stream>>>(OpartH, Mpart, Lpart, O,
                                                    chunk_tiles, max_chunks);
}

// Round 20
// 93.309 us; speedup vs baseline: 1.1168x; 1.1168x over previous
//
#include <hip/hip_runtime.h>
#include <hip/hip_bf16.h>

#define N_TOK 8192
#define D_IN  1024
#define DK    128
#define NT    256   // number of 32-row q tiles (== number of 32-row kv tiles)

typedef __attribute__((ext_vector_type(8))) short short8;
typedef __attribute__((ext_vector_type(4))) float f32x4;

static __device__ __forceinline__ unsigned short f2bf(float f) {
    __hip_bfloat16 h = __float2bfloat16(f);
    return __builtin_bit_cast(unsigned short, h);
}

static __device__ __forceinline__ void gl_lds16(const void* g, void* l) {
    __builtin_amdgcn_global_load_lds(
        (const __attribute__((address_space(1))) void*)g,
        (__attribute__((address_space(3))) void*)l, 16, 0, 0);
}

// ---------------- one-time W transpose: W[k][n] f32 -> Wt[n][k] bf16 ----------------
__global__ __launch_bounds__(256) void wtrans_kernel(
    const float* __restrict__ Wq, const float* __restrict__ Wk,
    const float* __restrict__ Wv, unsigned short* __restrict__ Wt)
{
    __shared__ unsigned short T[64][72];
    const int proj = blockIdx.y;
    const float* W = (proj == 0) ? Wq : (proj == 1) ? Wk : Wv;
    unsigned short* out = Wt + (size_t)proj * DK * D_IN;
    const int k0 = (blockIdx.x & 15) * 64, n0 = (blockIdx.x >> 4) * 64;
    const int tid = threadIdx.x;
    #pragma unroll
    for (int i = 0; i < 4; i++) {
        int e = tid + i * 256;
        int r = e >> 4, c4 = e & 15;
        float4 v = *reinterpret_cast<const float4*>(&W[(size_t)(k0 + r) * DK + n0 + c4 * 4]);
        T[c4 * 4 + 0][r] = f2bf(v.x);
        T[c4 * 4 + 1][r] = f2bf(v.y);
        T[c4 * 4 + 2][r] = f2bf(v.z);
        T[c4 * 4 + 3][r] = f2bf(v.w);
    }
    __syncthreads();
    #pragma unroll
    for (int i = 0; i < 4; i++) {
        int e = tid + i * 256;
        int r = e >> 4, c4 = e & 15;
        *reinterpret_cast<ushort4*>(&out[(size_t)(n0 + r) * D_IN + k0 + c4 * 4]) =
            *reinterpret_cast<const ushort4*>(&T[r][c4 * 4]);
    }
}

// ---------------- fused QKV projection: W stationary, X f32 direct, BK=128 ------
// grid = 768 = 128 row-blocks(64 rows) x 6 col-groups(64 cols), XCD-clustered.
// 8 k-steps of 128. X staged f32->bf16 via registers + swizzled ds_write
// (blk^(row&7), bijective per row). Q plain row-major; K 16B-block-swizzled
// (blk ^= kv&7); V transposed [d][kv] with (d&3) swizzle within 32-kv groups.
__global__ __launch_bounds__(256, 2) void proj_fused(
    const float* __restrict__ X, const unsigned short* __restrict__ Wt,
    const float* __restrict__ bq, const float* __restrict__ bk,
    const float* __restrict__ bv,
    unsigned short* __restrict__ Qb, unsigned short* __restrict__ Kb,
    unsigned short* __restrict__ Vt)
{
    __shared__ unsigned short Xs[2][64][128];   // 2 x 16 KB bf16

    const int bid = blockIdx.x;
    const int t2 = bid >> 3;
    const int rb = (t2 / 6) * 8 + (bid & 7);   // 0..127
    const int cg = t2 % 6;                     // 0..5

    const int tid = threadIdx.x;
    const int wid = tid >> 6, lane = tid & 63;
    const int g = lane >> 4, r16 = lane & 15;
    const int mb = rb * 64;
    const int colv = cg * 64 + wid * 16 + r16;   // global output col 0..383
    const int pj = colv >> 7;
    const int n  = colv & 127;

    // ---- W -> registers (once): 32 k-frags for this lane's column ----
    short8 wf[32];
    #pragma unroll
    for (int kd = 0; kd < 32; kd++)
        wf[kd] = *reinterpret_cast<const short8*>(
            &Wt[((size_t)pj * DK + n) * D_IN + kd * 32 + g * 8]);

    f32x4 acc[4] = {};

    // reg-staged X: 8 float4 per thread per step (64x128 f32 tile)
    float4 xr[8];
    const int xr_c4 = tid & 31;        // f32 float4-group 0..31 (constant per thread)
    auto XLOAD = [&](int s) {
        #pragma unroll
        for (int i = 0; i < 8; i++) {
            int r = (tid + i * 256) >> 5;          // 0..63
            xr[i] = *reinterpret_cast<const float4*>(
                &X[(size_t)(mb + r) * D_IN + s * 128 + xr_c4 * 4]);
        }
    };
    auto XWRITE = [&](int buf) {
        #pragma unroll
        for (int i = 0; i < 8; i++) {
            int r = (tid + i * 256) >> 5;
            ushort4 h;
            h.x = f2bf(xr[i].x); h.y = f2bf(xr[i].y);
            h.z = f2bf(xr[i].z); h.w = f2bf(xr[i].w);
            // 16B-bf16 block = c4>>1 (0..15), half = c4&1; swizzle low3 by row&7
            int off = (((xr_c4 >> 1) ^ (r & 7)) << 3) | ((xr_c4 & 1) << 2);
            *reinterpret_cast<ushort4*>(&Xs[buf][r][off]) = h;
        }
    };

    XLOAD(0); XWRITE(0);
    __syncthreads();
    #pragma unroll
    for (int s = 0; s < 8; ++s) {
        const int cur = s & 1;
        if (s + 1 < 8) XLOAD(s + 1);           // global->reg, overlaps compute
        #pragma unroll
        for (int kk = 0; kk < 4; kk++) {
            short8 af[4];
            #pragma unroll
            for (int mi = 0; mi < 4; mi++) {
                int blk = ((kk << 2) | g) ^ (r16 & 7);
                af[mi] = *reinterpret_cast<const short8*>(
                    &Xs[cur][mi * 16 + r16][blk * 8]);
            }
            __builtin_amdgcn_s_setprio(1);
            #pragma unroll
            for (int mi = 0; mi < 4; mi++)
                acc[mi] = __builtin_amdgcn_mfma_f32_16x16x32_bf16(
                    af[mi], wf[4 * s + kk], acc[mi], 0, 0, 0);
            __builtin_amdgcn_s_setprio(0);
        }
        if (s + 1 < 8) XWRITE((s + 1) & 1);    // buf^1: its reads ended last barrier
        __syncthreads();
    }

    const float* bias = (pj == 0) ? bq : (pj == 1) ? bk : bv;
    float b = bias[n];
    #pragma unroll
    for (int mi = 0; mi < 4; mi++) {
        if (pj < 2) {
            unsigned short* out = (pj == 0) ? Qb : Kb;
            #pragma unroll
            for (int e = 0; e < 4; e++) {
                int m = mb + mi * 16 + g * 4 + e;
                float val = acc[mi][e] + b;
                int nc = n;
                if (pj == 1)   // K swizzle: 16B block ^= (kv&7)
                    nc = ((((n >> 3) ^ (m & 7)) << 3) | (n & 7));
                out[(size_t)m * DK + nc] = f2bf(val);
            }
        } else {
            int m0 = mb + mi * 16 + g * 4;
            // V swizzle within 32-kv group: block' = ((m&31)>>3) ^ (d&3)
            int mblk = (((m0 & 31) >> 3) ^ (n & 3));
            int mp = (m0 & ~31) | (mblk << 3) | (m0 & 7);
            ushort4 h;
            h.x = f2bf(acc[mi][0] + b);
            h.y = f2bf(acc[mi][1] + b);
            h.z = f2bf(acc[mi][2] + b);
            h.w = f2bf(acc[mi][3] + b);
            *reinterpret_cast<ushort4*>(&Vt[(size_t)n * N_TOK + mp]) = h;
        }
    }
}

// ---------------- causal flash attention (R6/R13 champion, 56 µs) ----------------
// grid = (64 q-blocks, max_chunks). Block (qb,c): q rows [qb*128,+128), kv tiles
// [c*ct, min((c+1)*ct, 4qb+4)). 4 waves each own 32 q rows, share LDS K/V.
// Double-buffered global_load_lds with counted vmcnt(4); P via wave-private LDS;
// bf16 partials.
__global__ __launch_bounds__(256, 3) void attn_partial(
    const unsigned short* __restrict__ Qb, const unsigned short* __restrict__ Ksw,
    const unsigned short* __restrict__ Vsw,
    unsigned short* __restrict__ OpartH, float* __restrict__ Mpart,
    float* __restrict__ Lpart,
    float* __restrict__ O, int chunk_tiles, int max_chunks, int direct)
{
    __shared__ unsigned short Klds[2][32][128];   // 16 KB
    __shared__ unsigned short Vlds[2][128][32];   // 16 KB
    __shared__ unsigned short Pq[4][32][36];      // 9.2 KB, per-wave P[q][kv]

    const int qb = blockIdx.x, c = blockIdx.y;
    const int j0 = c * chunk_tiles;
    const int jmax = 4 * qb + 4;
    const int jend = min(j0 + chunk_tiles, jmax);
    if (j0 >= jend) return;
    const int nt = jend - j0;

    const int tid = threadIdx.x;
    const int wid = tid >> 6, lane = tid & 63;
    const int g = lane >> 4, r16 = lane & 15;
    const int t = qb * 4 + wid;     // this wave's 32-row q tile index
    const int qw = t * 32;          // global q base of this wave
    const float scale2 = 0.08838834764831845f * 1.4426950408889634f; // /sqrt(dk)*log2e

    auto STAGE = [&](int buf, int kvb) {   // exactly 4 gl_lds per thread
        #pragma unroll
        for (int s = 0; s < 2; s++) {                  // K: 8KB linear copy
            int ob = ((wid * 2 + s) << 10);
            gl_lds16((const char*)Ksw + ((size_t)kvb << 8) + ob + (lane << 4),
                     (char*)&Klds[buf][0][0] + ob);
        }
        #pragma unroll
        for (int s = 0; s < 2; s++) {                  // V: 128 rows x 64B
            int ob = ((wid * 2 + s) << 10);
            int o = ob + (lane << 4);
            int d = o >> 6, cb = o & 63;
            gl_lds16((const char*)Vsw + (((size_t)d * N_TOK + kvb) << 1) + cb,
                     (char*)&Vlds[buf][0][0] + ob);
        }
    };

    // Q fragments (B-operand): col=q=mi*16+r16, k=d
    short8 qf[2][4];
    #pragma unroll
    for (int mi = 0; mi < 2; mi++)
        #pragma unroll
        for (int kd = 0; kd < 4; kd++)
            qf[mi][kd] = *reinterpret_cast<const short8*>(
                &Qb[(size_t)(qw + mi * 16 + r16) * DK + kd * 32 + g * 8]);

    f32x4 o_acc[2][8] = {};                  // O^T: [q-frag mi][d-frag df]
    float m_run[2] = {-1e30f, -1e30f}, l_run[2] = {0.f, 0.f};

    STAGE(0, j0 * 32);

    int cur = 0;
    for (int it = 0; it < nt; ++it) {
        const int kvb = (j0 + it) * 32;
        if (it + 1 < nt) {
            STAGE(cur ^ 1, kvb + 32);
            asm volatile("s_waitcnt vmcnt(4)" ::: "memory");   // tile it landed
        } else {
            asm volatile("s_waitcnt vmcnt(0)" ::: "memory");
        }
        __builtin_amdgcn_sched_barrier(0);
        __builtin_amdgcn_s_barrier();
        __builtin_amdgcn_sched_barrier(0);

        const unsigned short* Kl = &Klds[cur][0][0];
        const unsigned short* Vl = &Vlds[cur][0][0];

        // ---- S^T = K Q^T from LDS (swizzled reads) ----
        f32x4 st[2][2] = {};                 // [ni=kv frag][mi=q frag]
        #pragma unroll
        for (int kd = 0; kd < 4; kd++) {
            int swb = ((((kd << 2) | g) ^ (r16 & 7)) << 3);
            short8 kf0 = *reinterpret_cast<const short8*>(Kl + r16 * 128 + swb);
            short8 kf1 = *reinterpret_cast<const short8*>(Kl + (16 + r16) * 128 + swb);
            __builtin_amdgcn_s_setprio(1);
            st[0][0] = __builtin_amdgcn_mfma_f32_16x16x32_bf16(kf0, qf[0][kd], st[0][0], 0, 0, 0);
            st[0][1] = __builtin_amdgcn_mfma_f32_16x16x32_bf16(kf0, qf[1][kd], st[0][1], 0, 0, 0);
            st[1][0] = __builtin_amdgcn_mfma_f32_16x16x32_bf16(kf1, qf[0][kd], st[1][0], 0, 0, 0);
            st[1][1] = __builtin_amdgcn_mfma_f32_16x16x32_bf16(kf1, qf[1][kd], st[1][1], 0, 0, 0);
            __builtin_amdgcn_s_setprio(0);
        }

        // ---- online softmax (exp2 domain), per q-column (mi,r16) ----
        const bool anymask = (kvb + 31 > qw);
        float alpha[2];
        #pragma unroll
        for (int mi = 0; mi < 2; mi++) {
            const int qrow = qw + mi * 16 + r16;
            float s[2][4];
            #pragma unroll
            for (int ni = 0; ni < 2; ni++)
                #pragma unroll
                for (int e = 0; e < 4; e++) {
                    float v = st[ni][mi][e] * scale2;
                    if (anymask && (kvb + ni * 16 + g * 4 + e > qrow)) v = -1e30f;
                    s[ni][e] = v;
                }
            float lm = fmaxf(fmaxf(fmaxf(s[0][0], s[0][1]), fmaxf(s[0][2], s[0][3])),
                             fmaxf(fmaxf(s[1][0], s[1][1]), fmaxf(s[1][2], s[1][3])));
            lm = fmaxf(lm, __shfl_xor(lm, 16));
            lm = fmaxf(lm, __shfl_xor(lm, 32));
            float mnew = fmaxf(m_run[mi], lm);
            alpha[mi] = exp2f(m_run[mi] - mnew);
            float ps[2][4];
            #pragma unroll
            for (int ni = 0; ni < 2; ni++)
                #pragma unroll
                for (int e = 0; e < 4; e++)
                    ps[ni][e] = exp2f(s[ni][e] - mnew);
            float ls = ((ps[0][0] + ps[0][1]) + (ps[0][2] + ps[0][3]))
                     + ((ps[1][0] + ps[1][1]) + (ps[1][2] + ps[1][3]));
            ls += __shfl_xor(ls, 16);
            ls += __shfl_xor(ls, 32);
            l_run[mi] = l_run[mi] * alpha[mi] + ls;
            m_run[mi] = mnew;
            #pragma unroll
            for (int ni = 0; ni < 2; ni++) {
                ushort4 pk;
                pk.x = f2bf(ps[ni][0]); pk.y = f2bf(ps[ni][1]);
                pk.z = f2bf(ps[ni][2]); pk.w = f2bf(ps[ni][3]);
                *reinterpret_cast<ushort4*>(&Pq[wid][mi * 16 + r16][ni * 16 + g * 4]) = pk;
            }
        }
        if (__any(alpha[0] < 1.f) || __any(alpha[1] < 1.f)) {
            #pragma unroll
            for (int mi = 0; mi < 2; mi++)
                #pragma unroll
                for (int df = 0; df < 8; df++)
                    #pragma unroll
                    for (int e = 0; e < 4; e++)
                        o_acc[mi][df][e] *= alpha[mi];
        }
        // P^T B-fragments: col=q=r16, k=kv=g*8+idx (wave-private Pq: no barrier)
        short8 pb0 = *reinterpret_cast<const short8*>(&Pq[wid][r16][g * 8]);
        short8 pb1 = *reinterpret_cast<const short8*>(&Pq[wid][16 + r16][g * 8]);
        // ---- O^T += V^T P^T, V from LDS (swizzled reads) ----
        const int swv = ((g ^ (r16 & 3)) << 3);
        #pragma unroll
        for (int df = 0; df < 8; df++) {
            short8 vf = *reinterpret_cast<const short8*>(Vl + (df * 16 + r16) * 32 + swv);
            __builtin_amdgcn_s_setprio(1);
            o_acc[0][df] = __builtin_amdgcn_mfma_f32_16x16x32_bf16(vf, pb0, o_acc[0][df], 0, 0, 0);
            o_acc[1][df] = __builtin_amdgcn_mfma_f32_16x16x32_bf16(vf, pb1, o_acc[1][df], 0, 0, 0);
            __builtin_amdgcn_s_setprio(0);
        }

        __builtin_amdgcn_sched_barrier(0);
        __builtin_amdgcn_s_barrier();      // all waves done reading buf[cur]
        __builtin_amdgcn_sched_barrier(0);
        cur ^= 1;
    }

    // ---- epilogue: direct f32 out, else bf16 partials ----
    if (direct) {
        #pragma unroll
        for (int mi = 0; mi < 2; mi++) {
            float inv = 1.0f / l_run[mi];
            #pragma unroll
            for (int df = 0; df < 8; df++) {
                f32x4 r = o_acc[mi][df];
                r[0] *= inv; r[1] *= inv; r[2] *= inv; r[3] *= inv;
                *reinterpret_cast<f32x4*>(
                    &O[(size_t)(qw + mi * 16 + r16) * DK + df * 16 + g * 4]) = r;
            }
        }
    } else {
        size_t pb0i = ((size_t)t * max_chunks + c) * 32;
        #pragma unroll
        for (int mi = 0; mi < 2; mi++) {
            int q = mi * 16 + r16;
            #pragma unroll
            for (int df = 0; df < 8; df++) {
                ushort4 h;
                h.x = f2bf(o_acc[mi][df][0]); h.y = f2bf(o_acc[mi][df][1]);
                h.z = f2bf(o_acc[mi][df][2]); h.w = f2bf(o_acc[mi][df][3]);
                *reinterpret_cast<ushort4*>(
                    &OpartH[(pb0i + q) * 128 + df * 16 + g * 4]) = h;
            }
            if (g == 0) { Mpart[pb0i + q] = m_run[mi]; Lpart[pb0i + q] = l_run[mi]; }
        }
    }
}

// ---------------- merge bf16 partials across chunks (exp2, d-split 2x) ----------
// grid = (NT, 2): block (t, half) merges rows of q-tile t for cols half*64..+64.
__global__ __launch_bounds__(256) void attn_merge(
    const unsigned short* __restrict__ OpartH, const float* __restrict__ Mpart,
    const float* __restrict__ Lpart, float* __restrict__ O,
    int chunk_tiles, int max_chunks)
{
    __shared__ float Ms[32], Ls[32], Fs[16][32];
    const int t = blockIdx.x;
    const int half = blockIdx.y;
    const int nc = t / chunk_tiles + 1;
    const int tid = threadIdx.x;

    if (tid < 32) {
        float M = -1e30f;
        for (int c = 0; c < nc; c++)
            M = fmaxf(M, Mpart[((size_t)t * max_chunks + c) * 32 + tid]);
        float L = 0.f;
        for (int c = 0; c < nc; c++) {
            size_t pb = ((size_t)t * max_chunks + c) * 32 + tid;
            L += exp2f(Mpart[pb] - M) * Lpart[pb];
        }
        Ms[tid] = M; Ls[tid] = L;
    }
    __syncthreads();
    for (int cc = tid >> 5; cc < nc; cc += 8) {
        int row = tid & 31;
        Fs[cc][row] = exp2f(Mpart[((size_t)t * max_chunks + cc) * 32 + row] - Ms[row]);
    }
    __syncthreads();
    {
        int row = tid >> 3;                       // 32 rows x 8 col-groups of 8
        int c8 = (tid & 7) + half * 8;            // this block's 64-col half
        float accv[8] = {};
        for (int c = 0; c < nc; c++) {
            short8 u = *reinterpret_cast<const short8*>(
                &OpartH[(((size_t)t * max_chunks + c) * 32 + row) * 128 + c8 * 8]);
            float f = Fs[c][row];
            #pragma unroll
            for (int k = 0; k < 8; k++) {
                unsigned uv = ((unsigned)(unsigned short)u[k]) << 16;
                accv[k] += f * __builtin_bit_cast(float, uv);
            }
        }
        float inv = 1.0f / Ls[row];
        float* dst = &O[((size_t)t * 32 + row) * DK + c8 * 8];
        float4 r0 = {accv[0] * inv, accv[1] * inv, accv[2] * inv, accv[3] * inv};
        float4 r1 = {accv[4] * inv, accv[5] * inv, accv[6] * inv, accv[7] * inv};
        *reinterpret_cast<float4*>(dst) = r0;
        *reinterpret_cast<float4*>(dst + 4) = r1;
    }
}

extern "C" void kernel_launch(void* const* d_in, const int* in_sizes, int n_in,
                              void* d_out, int out_size, void* d_ws, size_t ws_size,
                              hipStream_t stream) {
    const float* X  = (const float*)d_in[0];
    const float* Wq = (const float*)d_in[1];
    const float* bq = (const float*)d_in[2];
    const float* Wk = (const float*)d_in[3];
    const float* bk = (const float*)d_in[4];
    const float* Wv = (const float*)d_in[5];
    const float* bv = (const float*)d_in[6];
    float* O = (float*)d_out;

    unsigned short* Qb = (unsigned short*)d_ws;
    unsigned short* Kb = Qb + (size_t)N_TOK * DK;
    unsigned short* Vt = Kb + (size_t)N_TOK * DK;
    unsigned short* Wt = Vt + (size_t)N_TOK * DK;
    float* Mbase = (float*)(Wt + (size_t)3 * DK * D_IN);
    size_t base_bytes = (size_t)((char*)Mbase - (char*)d_ws);

    // ladder: pick smallest chunk whose partials fit ws
    int chunk_tiles = 0, max_chunks = 1, direct = 0;
    const int opts[4] = {16, 32, 64, 128};
    for (int i = 0; i < 4; i++) {
        int ct = opts[i], mc = NT / ct;
        size_t need = base_bytes
                    + (size_t)NT * mc * 32 * 2 * sizeof(float)      // M, L
                    + (size_t)NT * mc * 32 * 128 * 2;               // Opart bf16
        if (need <= ws_size) { chunk_tiles = ct; max_chunks = mc; break; }
    }
    if (!chunk_tiles) { chunk_tiles = NT; max_chunks = 1; direct = 1; }
    float* Mpart = Mbase;
    float* Lpart = Mpart + (size_t)NT * max_chunks * 32;
    unsigned short* OpartH = (unsigned short*)(Lpart + (size_t)NT * max_chunks * 32);

    wtrans_kernel<<<dim3(32, 3), 256, 0, stream>>>(Wq, Wk, Wv, Wt);
    proj_fused<<<dim3(768), 256, 0, stream>>>(X, Wt, bq, bk, bv, Qb, Kb, Vt);
    int grid_c = direct ? 1 : max_chunks;
    attn_partial<<<dim3(64, grid_c), 256, 0, stream>>>(
        Qb, Kb, Vt, OpartH, Mpart, Lpart, O, chunk_tiles, max_chunks, direct);
    if (!direct)
        attn_merge<<<dim3(NT, 2), 256, 0, stream>>>(OpartH, Mpart, Lpart, O,
                                                    chunk_tiles, max_chunks);
}